// Round 9
// baseline (567.864 us; speedup 1.0000x reference)
//
#include <hip/hip_runtime.h>
#include <math.h>

#define NG 100000
#define ND 50000
#define NTOT 150000
#define DIM 128
#define NE 800000
#define EPSN 1e-12f

#define RPB 128     // rows per sage block
#define NBT_D3 391  // ceil(ND/128)
#define NBT_G3 782  // ceil(NG/128)

#define NBK 586  // ceil(NTOT/256) scan chunks of 256 nodes

typedef __bf16 bf16x8 __attribute__((ext_vector_type(8)));
typedef float f32x4 __attribute__((ext_vector_type(4)));
typedef unsigned int uint32;

__device__ __forceinline__ ushort rne_bf16(float f) {
  uint32 u = __builtin_bit_cast(uint32, f);
  u += 0x7fffu + ((u >> 16) & 1u);
  return (ushort)(u >> 16);
}

// async global->LDS, 16B per lane; LDS dest is wave-uniform base + lane*16
__device__ __forceinline__ void gload_lds16(const void* g, void* l) {
  __builtin_amdgcn_global_load_lds((const __attribute__((address_space(1))) void*)g,
                                   (__attribute__((address_space(3))) void*)l, 16, 0, 0);
}

// ---------------- direct-to-CSR build (no pairs round-trip) ----------------
// unified dst space: disease dsts [0,ND), gene dsts [ND,NTOT).

__global__ void zero_ints(int* __restrict__ p, int n) {
  int i = blockIdx.x * 256 + threadIdx.x;
  if (i < n) p[i] = 0;
}

// per-node degree via global atomics (600 KB counter array, L2-resident)
__global__ void count_edges(const int* __restrict__ dst_g2d, const int* __restrict__ dst_d2g,
                            int* __restrict__ cnt) {
  int i = blockIdx.x * 256 + threadIdx.x;
  if (i >= 2 * NE) return;
  int d = (i < NE) ? dst_g2d[i] : ND + dst_d2g[i - NE];
  atomicAdd(&cnt[d], 1);
}

// per-256-node chunk exclusive scan; chunk totals to bsum
__global__ void scan_local(const int* __restrict__ cnt, int* __restrict__ loc,
                           int* __restrict__ bsum) {
  __shared__ int ss[256];
  int b = blockIdx.x, t = threadIdx.x;
  int idx = b * 256 + t;
  int c = (idx < NTOT) ? cnt[idx] : 0;
  ss[t] = c;
  __syncthreads();
  for (int o = 1; o < 256; o <<= 1) {
    int y = (t >= o) ? ss[t - o] : 0;
    __syncthreads();
    ss[t] += y;
    __syncthreads();
  }
  if (idx < NTOT) loc[idx] = ss[t] - c;
  if (t == 255) bsum[b] = ss[255];
}

// exclusive scan of the 586 chunk totals
__global__ void scan_blocks(const int* __restrict__ bsum, int* __restrict__ bbase) {
  __shared__ int s[1024];
  int t = threadIdx.x;
  s[t] = (t < NBK) ? bsum[t] : 0;
  __syncthreads();
  for (int off = 1; off < 1024; off <<= 1) {
    int v = (t >= off) ? s[t - off] : 0;
    __syncthreads();
    s[t] += v;
    __syncthreads();
  }
  if (t < NBK) bbase[t] = (t > 0) ? s[t - 1] : 0;
}

// off[i] = chunk base + local exclusive; cur[i] = copy (scatter cursor)
__global__ void finalize_off(int* __restrict__ off, const int* __restrict__ bbase,
                             int* __restrict__ cur) {
  int i = blockIdx.x * 256 + threadIdx.x;
  if (i < NTOT) {
    int v = off[i] + bbase[i >> 8];
    off[i] = v;
    cur[i] = v;
  }
  if (i == 0) off[NTOT] = 2 * NE;
}

// scatter srcs directly into csr via per-node cursors (full-width grid)
__global__ void scatter_edges(const int* __restrict__ src_g2d, const int* __restrict__ dst_g2d,
                              const int* __restrict__ src_d2g, const int* __restrict__ dst_d2g,
                              int* __restrict__ cur, int* __restrict__ csr) {
  int i = blockIdx.x * 256 + threadIdx.x;
  if (i >= 2 * NE) return;
  int d, s;
  if (i < NE) {
    d = dst_g2d[i];
    s = src_g2d[i];
  } else {
    d = ND + dst_d2g[i - NE];
    s = src_d2g[i - NE];
  }
  int p = atomicAdd(&cur[d], 1);
  csr[p] = s;
}

// ---------------- fp32 -> bf16 table convert (RNE), both tables in one launch ------------

__global__ void to_bf16_all(const float* __restrict__ xg, const float* __restrict__ xd,
                            ushort* __restrict__ yg, ushort* __restrict__ yd) {
  int i = blockIdx.x * 256 + threadIdx.x;
  if (i >= NTOT * 16) return;
  const float* x;
  ushort* y;
  int j;
  if (i < NG * 16) {
    x = xg; y = yg; j = i;
  } else {
    x = xd; y = yd; j = i - NG * 16;
  }
  const float4* px = (const float4*)x;
  float4 a = px[2 * j], b = px[2 * j + 1];
  float v[8] = {a.x, a.y, a.z, a.w, b.x, b.y, b.z, b.w};
  uint32 u[4];
#pragma unroll
  for (int k = 0; k < 4; k++)
    u[k] = (uint32)rne_bf16(v[2 * k]) | ((uint32)rne_bf16(v[2 * k + 1]) << 16);
  ((int4*)y)[j] = make_int4((int)u[0], (int)u[1], (int)u[2], (int)u[3]);
}

// ---------------- W pre-split: fp32 -> bf16 hi (trunc) + bf16 lo (residual) --------------

__global__ void split_w(const float* __restrict__ Wl, const float* __restrict__ Wr,
                        ushort* __restrict__ WlH, ushort* __restrict__ WlL,
                        ushort* __restrict__ WrH, ushort* __restrict__ WrL) {
  int i = blockIdx.x * 256 + threadIdx.x;
  if (i >= 4 * 128 * 128) return;
  {
    float a = Wl[i];
    uint32 u = __builtin_bit_cast(uint32, a);
    float hf = __builtin_bit_cast(float, u & 0xffff0000u);
    WlH[i] = (ushort)(u >> 16);
    WlL[i] = (ushort)(__builtin_bit_cast(uint32, a - hf) >> 16);
  }
  {
    float a = Wr[i];
    uint32 u = __builtin_bit_cast(uint32, a);
    float hf = __builtin_bit_cast(float, u & 0xffff0000u);
    WrH[i] = (ushort)(u >> 16);
    WrL[i] = (ushort)(__builtin_bit_cast(uint32, a - hf) >> 16);
  }
}

// ---------------- mean aggregation over bf16 rows, unified node space --------------------
// 16 lanes per node (4 nodes per wave), 8-deep edge unroll.

__device__ __forceinline__ void acc8(float* a, int4 u) {
  uint32 w;
  w = (uint32)u.x;
  a[0] += __builtin_bit_cast(float, w << 16);
  a[1] += __builtin_bit_cast(float, w & 0xffff0000u);
  w = (uint32)u.y;
  a[2] += __builtin_bit_cast(float, w << 16);
  a[3] += __builtin_bit_cast(float, w & 0xffff0000u);
  w = (uint32)u.z;
  a[4] += __builtin_bit_cast(float, w << 16);
  a[5] += __builtin_bit_cast(float, w & 0xffff0000u);
  w = (uint32)u.w;
  a[6] += __builtin_bit_cast(float, w << 16);
  a[7] += __builtin_bit_cast(float, w & 0xffff0000u);
}

__global__ void agg_comb(const ushort* __restrict__ xg_bf, const ushort* __restrict__ xd_bf,
                         const int* __restrict__ off, const int* __restrict__ csr,
                         ushort* __restrict__ agg_bf) {
  int node = (blockIdx.x * 256 + threadIdx.x) >> 4;
  if (node >= NTOT) return;
  int l16 = threadIdx.x & 15;
  const int4* xs = (const int4*)((node < ND) ? xg_bf : xd_bf);
  int e0 = off[node], e1 = off[node + 1];
  float a[8] = {0.f, 0.f, 0.f, 0.f, 0.f, 0.f, 0.f, 0.f};
  int e = e0;
  for (; e + 7 < e1; e += 8) {
    int s[8];
#pragma unroll
    for (int j = 0; j < 8; j++) s[j] = csr[e + j];
    int4 v[8];
#pragma unroll
    for (int j = 0; j < 8; j++) v[j] = xs[(size_t)s[j] * 16 + l16];
#pragma unroll
    for (int j = 0; j < 8; j++) acc8(a, v[j]);
  }
  for (; e + 3 < e1; e += 4) {
    int s0 = csr[e], s1 = csr[e + 1], s2 = csr[e + 2], s3 = csr[e + 3];
    int4 v0 = xs[(size_t)s0 * 16 + l16];
    int4 v1 = xs[(size_t)s1 * 16 + l16];
    int4 v2 = xs[(size_t)s2 * 16 + l16];
    int4 v3 = xs[(size_t)s3 * 16 + l16];
    acc8(a, v0);
    acc8(a, v1);
    acc8(a, v2);
    acc8(a, v3);
  }
  for (; e + 1 < e1; e += 2) {
    int s0 = csr[e], s1 = csr[e + 1];
    int4 v0 = xs[(size_t)s0 * 16 + l16];
    int4 v1 = xs[(size_t)s1 * 16 + l16];
    acc8(a, v0);
    acc8(a, v1);
  }
  if (e < e1) acc8(a, xs[(size_t)csr[e] * 16 + l16]);
  int deg = e1 - e0;
  float inv = (deg > 0) ? 1.f / (float)deg : 0.f;
  uint32 u[4];
#pragma unroll
  for (int j = 0; j < 4; j++)
    u[j] = (uint32)rne_bf16(a[2 * j] * inv) | ((uint32)rne_bf16(a[2 * j + 1] * inv) << 16);
  *(int4*)&agg_bf[(size_t)node * DIM + l16 * 8] =
      make_int4((int)u[0], (int)u[1], (int)u[2], (int)u[3]);
}

// ---------------- MFMA SAGE update: acc[2][8], spill-free with full prefetch -------------
// (unchanged from R8 winner: WRITE_SIZE==112500 exactly, 65 us/dispatch)

__device__ __forceinline__ void split8v(float4 f0, float4 f1, bf16x8& hi, bf16x8& lo) {
  float v[8] = {f0.x, f0.y, f0.z, f0.w, f1.x, f1.y, f1.z, f1.w};
  uint32 hw[4], lw[4];
#pragma unroll
  for (int j = 0; j < 4; j++) {
    uint32 u0 = __builtin_bit_cast(uint32, v[2 * j]);
    uint32 u1 = __builtin_bit_cast(uint32, v[2 * j + 1]);
    float hf0 = __builtin_bit_cast(float, u0 & 0xffff0000u);
    float hf1 = __builtin_bit_cast(float, u1 & 0xffff0000u);
    uint32 l0 = __builtin_bit_cast(uint32, v[2 * j] - hf0) >> 16;
    uint32 l1 = __builtin_bit_cast(uint32, v[2 * j + 1] - hf1) >> 16;
    hw[j] = (u0 >> 16) | ((u1 >> 16) << 16);
    lw[j] = l0 | (l1 << 16);
  }
  hi = __builtin_bit_cast(bf16x8, make_int4((int)hw[0], (int)hw[1], (int)hw[2], (int)hw[3]));
  lo = __builtin_bit_cast(bf16x8, make_int4((int)lw[0], (int)lw[1], (int)lw[2], (int)lw[3]));
}

__launch_bounds__(256, 2)
__global__ void sage_dual(const ushort* __restrict__ agg_bf, const float* __restrict__ xd,
                          const float* __restrict__ xg, const ushort* __restrict__ WlH,
                          const ushort* __restrict__ WlL, const ushort* __restrict__ WrH,
                          const ushort* __restrict__ WrL, const float* __restrict__ bias_all,
                          float* __restrict__ outd, float* __restrict__ outg,
                          ushort* __restrict__ xbf_d, ushort* __restrict__ xbf_g, int layer,
                          int relu, int write_bf) {
  __shared__ __align__(16) char smem[65536];  // [hi 32K][lo 32K] of current phase's W

  int b = blockIdx.x;
  const float* X;
  float* O;
  ushort* OBF;
  int n, set, r0g, cbase;
  if (b < NBT_D3) {
    X = xd; O = outd; OBF = xbf_d; n = ND; set = layer * 2; r0g = b * RPB; cbase = 0;
  } else {
    X = xg; O = outg; OBF = xbf_g; n = NG; set = layer * 2 + 1;
    r0g = (b - NBT_D3) * RPB; cbase = ND;
  }
  const ushort* Wplanes[4] = {WlH + set * 16384, WlL + set * 16384, WrH + set * 16384,
                              WrL + set * 16384};
  const float* bias = bias_all + set * 128;

  int tid = threadIdx.x;
  int wave = tid >> 6, lane = tid & 63;
  int m = lane & 15, q = lane >> 4;
  int rb = r0g + wave * 32;

  int rp[2];
#pragma unroll
  for (int mt = 0; mt < 2; mt++) {
    int r = rb + mt * 16 + m;
    rp[mt] = (r >= n) ? (n - 1) : r;
  }

  // async stage hi/lo W planes: wave w covers 1KB chunks [w*16, w*16+16)
  auto stageW_async = [&](const ushort* Ph, const ushort* Pl) {
#pragma unroll
    for (int i = 0; i < 16; i++) {
      int cc = wave * 16 + i;            // 1KB chunk 0..63
      int dstb = cc * 1024 + lane * 16;  // linear LDS byte
      int p = cc >> 5;                   // plane (chunks don't straddle)
      int pb = dstb & 32767;
      int srcb = pb ^ (((pb >> 8) & 7) << 4);  // inverse swizzle on source
      const char* src = (const char*)(p ? Pl : Ph) + srcb;
      gload_lds16(src, smem + cc * 1024);
    }
  };

  // ---- prologue: issue Wl DMA + ALL ph0 A fragments (overlapped) ----
  stageW_async(Wplanes[0], Wplanes[1]);
  int4 aV[4][2];
#pragma unroll
  for (int ks = 0; ks < 4; ks++)
#pragma unroll
    for (int mt = 0; mt < 2; mt++)
      aV[ks][mt] = *(const int4*)&agg_bf[(size_t)(cbase + rp[mt]) * DIM + ks * 32 + q * 8];
  __syncthreads();  // drains vmcnt: DMA + A prefetch complete

  f32x4 acc[2][8];
#pragma unroll
  for (int mt = 0; mt < 2; mt++)
#pragma unroll
    for (int nt = 0; nt < 8; nt++) acc[mt][nt] = (f32x4)0.f;

  // ---- ph0: pure LDS + MFMA ----
#pragma unroll
  for (int ks = 0; ks < 4; ks++) {
    int kb = ks * 64 + q * 16;
#pragma unroll
    for (int nt = 0; nt < 8; nt++) {
      int nn = nt * 16 + m;
      int wb = (nn * 256 + kb) ^ ((nn & 7) << 4);
      bf16x8 bh = *(const bf16x8*)(smem + wb);
      bf16x8 bl = *(const bf16x8*)(smem + 32768 + wb);
#pragma unroll
      for (int mt = 0; mt < 2; mt++) {
        bf16x8 a = __builtin_bit_cast(bf16x8, aV[ks][mt]);
        acc[mt][nt] = __builtin_amdgcn_mfma_f32_16x16x32_bf16(a, bh, acc[mt][nt], 0, 0, 0);
        acc[mt][nt] = __builtin_amdgcn_mfma_f32_16x16x32_bf16(a, bl, acc[mt][nt], 0, 0, 0);
      }
    }
  }

  // ---- transition: issue ks0 X loads, then barrier, then Wr DMA ----
  float4 xV[2][2];
#pragma unroll
  for (int mt = 0; mt < 2; mt++) {
#pragma unroll
    for (int h = 0; h < 2; h++)
      xV[mt][h] = *(const float4*)&X[(size_t)rp[mt] * DIM + q * 8 + h * 4];
  }
  __syncthreads();  // ph0 LDS reads done (xV completes here too)
  stageW_async(Wplanes[2], Wplanes[3]);
  __syncthreads();  // Wr DMA complete

  // ---- ph1: root X, distance-1 prefetch of next ks ----
#pragma unroll
  for (int ks = 0; ks < 4; ks++) {
    int kb = ks * 64 + q * 16;
    bf16x8 ah[2], al[2];
#pragma unroll
    for (int mt = 0; mt < 2; mt++) split8v(xV[mt][0], xV[mt][1], ah[mt], al[mt]);
    if (ks < 3) {
#pragma unroll
      for (int mt = 0; mt < 2; mt++) {
#pragma unroll
        for (int h = 0; h < 2; h++)
          xV[mt][h] = *(const float4*)&X[(size_t)rp[mt] * DIM + (ks + 1) * 32 + q * 8 + h * 4];
      }
    }
#pragma unroll
    for (int nt = 0; nt < 8; nt++) {
      int nn = nt * 16 + m;
      int wb = (nn * 256 + kb) ^ ((nn & 7) << 4);
      bf16x8 bh = *(const bf16x8*)(smem + wb);
      bf16x8 bl = *(const bf16x8*)(smem + 32768 + wb);
#pragma unroll
      for (int mt = 0; mt < 2; mt++) {
        acc[mt][nt] = __builtin_amdgcn_mfma_f32_16x16x32_bf16(ah[mt], bh, acc[mt][nt], 0, 0, 0);
        acc[mt][nt] = __builtin_amdgcn_mfma_f32_16x16x32_bf16(ah[mt], bl, acc[mt][nt], 0, 0, 0);
        acc[mt][nt] = __builtin_amdgcn_mfma_f32_16x16x32_bf16(al[mt], bh, acc[mt][nt], 0, 0, 0);
      }
    }
  }
  __syncthreads();  // all waves done reading W LDS; epilogue aliases it

  // ---- epilogue: bias, relu, L2-normalize, skipsum, store (+ optional bf16 copy) ----
  float bb[8];
#pragma unroll
  for (int nt = 0; nt < 8; nt++) bb[nt] = bias[nt * 16 + m];

  const int S = 132;
  float* wbuf = (float*)smem + wave * (16 * S);  // wave-private: no barriers needed

  int half = lane >> 5;
  int c4 = (lane & 31) * 4;

#pragma unroll
  for (int mt = 0; mt < 2; mt++) {
#pragma unroll
    for (int reg = 0; reg < 4; reg++) {
      float h[8];
      float ss = 0.f;
#pragma unroll
      for (int nt = 0; nt < 8; nt++) {
        float v = acc[mt][nt][reg] + bb[nt];
        if (relu) v = fmaxf(v, 0.f);
        h[nt] = v;
        ss += v * v;
      }
      ss += __shfl_xor(ss, 1);
      ss += __shfl_xor(ss, 2);
      ss += __shfl_xor(ss, 4);
      ss += __shfl_xor(ss, 8);
      float inv = 1.f / fmaxf(sqrtf(ss), EPSN);
      int rrel = q * 4 + reg;
#pragma unroll
      for (int nt = 0; nt < 8; nt++) wbuf[rrel * S + nt * 16 + m] = h[nt] * inv;
    }
#pragma unroll
    for (int i = 0; i < 8; i++) {
      int rrel = i * 2 + half;
      int R = rb + mt * 16 + rrel;
      if (R < n) {
        f32x4 hv = *(const f32x4*)&wbuf[rrel * S + c4];
        float4 xr = *(const float4*)&X[(size_t)R * DIM + c4];
        float4 o;
        o.x = hv[0] + xr.x;
        o.y = hv[1] + xr.y;
        o.z = hv[2] + xr.z;
        o.w = hv[3] + xr.w;
        *(float4*)&O[(size_t)R * DIM + c4] = o;
        if (write_bf) {
          int2 pk = make_int2((int)((uint32)rne_bf16(o.x) | ((uint32)rne_bf16(o.y) << 16)),
                              (int)((uint32)rne_bf16(o.z) | ((uint32)rne_bf16(o.w) << 16)));
          *(int2*)&OBF[(size_t)R * DIM + c4] = pk;
        }
      }
    }
  }
}

// ---------------- launch ----------------

extern "C" void kernel_launch(void* const* d_in, const int* in_sizes, int n_in,
                              void* d_out, int out_size, void* d_ws, size_t ws_size,
                              hipStream_t stream) {
  const float* xg0 = (const float*)d_in[0];
  const float* xd0 = (const float*)d_in[1];
  const float* Wl = (const float*)d_in[2];
  const float* Wr = (const float*)d_in[3];
  const float* bs = (const float*)d_in[4];
  const int* src_g2d = (const int*)d_in[5];
  const int* dst_g2d = (const int*)d_in[6];
  const int* src_d2g = (const int*)d_in[7];
  const int* dst_d2g = (const int*)d_in[8];

  float* out_xg = (float*)d_out;
  float* out_xd = (float*)d_out + (size_t)NG * DIM;

  char* p = (char*)d_ws;
  auto alloc = [&](size_t bytes) -> char* {
    char* q = p;
    p += (bytes + 255) & ~(size_t)255;
    return q;
  };
  int* off = (int*)alloc((NTOT + 1) * 4);
  int* csr = (int*)alloc((size_t)2 * NE * 4);
  int* cur = (int*)alloc(NTOT * 4);  // degree counts, then scatter cursors
  int* bsum = (int*)alloc(NBK * 4);
  int* bbase = (int*)alloc((NBK + 1) * 4);
  ushort* agg_bf = (ushort*)alloc((size_t)NTOT * DIM * 2);
  ushort* xg_bf = (ushort*)alloc((size_t)NG * DIM * 2);
  ushort* xd_bf = (ushort*)alloc((size_t)ND * DIM * 2);
  ushort* WlH = (ushort*)alloc((size_t)4 * 128 * 128 * 2);
  ushort* WlL = (ushort*)alloc((size_t)4 * 128 * 128 * 2);
  ushort* WrH = (ushort*)alloc((size_t)4 * 128 * 128 * 2);
  ushort* WrL = (ushort*)alloc((size_t)4 * 128 * 128 * 2);

  const int TB = 256;
  const int EB = (2 * NE + TB - 1) / TB;  // 6250 edge blocks

  split_w<<<256, TB, 0, stream>>>(Wl, Wr, WlH, WlL, WrH, WrL);
  to_bf16_all<<<(NTOT * 16 + TB - 1) / TB, TB, 0, stream>>>(xg0, xd0, xg_bf, xd_bf);

  // direct-to-CSR build
  zero_ints<<<(NTOT + TB - 1) / TB, TB, 0, stream>>>(cur, NTOT);
  count_edges<<<EB, TB, 0, stream>>>(dst_g2d, dst_d2g, cur);
  scan_local<<<NBK, TB, 0, stream>>>(cur, off, bsum);
  scan_blocks<<<1, 1024, 0, stream>>>(bsum, bbase);
  finalize_off<<<NBK, TB, 0, stream>>>(off, bbase, cur);
  scatter_edges<<<EB, TB, 0, stream>>>(src_g2d, dst_g2d, src_d2g, dst_d2g, cur, csr);

  int aggBlocks = (NTOT * 16 + TB - 1) / TB;  // 9375 (16 lanes per node)
  int sageBlocks = NBT_D3 + NBT_G3;           // 1173

  // layer 0 (relu); sage also emits bf16 copy of out for layer-1 gather
  agg_comb<<<aggBlocks, TB, 0, stream>>>(xg_bf, xd_bf, off, csr, agg_bf);
  sage_dual<<<sageBlocks, TB, 0, stream>>>(agg_bf, xd0, xg0, WlH, WlL, WrH, WrL, bs, out_xd,
                                           out_xg, xd_bf, xg_bf, 0, 1, 1);

  // layer 1 (no relu), in-place on d_out
  agg_comb<<<aggBlocks, TB, 0, stream>>>(xg_bf, xd_bf, off, csr, agg_bf);
  sage_dual<<<sageBlocks, TB, 0, stream>>>(agg_bf, out_xd, out_xg, WlH, WlL, WrH, WrL, bs,
                                           out_xd, out_xg, xd_bf, xg_bf, 1, 0, 0);
}

// Round 10
// 441.758 us; speedup vs baseline: 1.2855x; 1.2855x over previous
//
#include <hip/hip_runtime.h>
#include <math.h>

#define NG 100000
#define ND 50000
#define NTOT 150000
#define DIM 128
#define NE 800000
#define EPSN 1e-12f

#define RPB 128     // rows per sage block
#define NBT_D3 391  // ceil(ND/128)
#define NBT_G3 782  // ceil(NG/128)

#define NBK 586   // ceil(NTOT/256) buckets of 256 dst nodes
#define SCB 512   // scatter blocks (2 blocks/CU; was 128 = 0.5/CU)
#define EPB 3125  // edges per scatter block = 2*NE/SCB

typedef __bf16 bf16x8 __attribute__((ext_vector_type(8)));
typedef float f32x4 __attribute__((ext_vector_type(4)));
typedef unsigned int uint32;

__device__ __forceinline__ ushort rne_bf16(float f) {
  uint32 u = __builtin_bit_cast(uint32, f);
  u += 0x7fffu + ((u >> 16) & 1u);
  return (ushort)(u >> 16);
}

// async global->LDS, 16B per lane; LDS dest is wave-uniform base + lane*16
__device__ __forceinline__ void gload_lds16(const void* g, void* l) {
  __builtin_amdgcn_global_load_lds((const __attribute__((address_space(1))) void*)g,
                                   (__attribute__((address_space(3))) void*)l, 16, 0, 0);
}

// ---------------- bucketed CSR build ----------------
// unified dst space: disease dsts [0,ND), gene dsts [ND,NTOT). bucket = dst>>8.
// Two-phase (pairs intermediate) is deliberate: all writes are bucket-contiguous
// cache lines. R9's direct scatter_edges (random 4B csr writes) cost 17x write
// amplification (109 MB for a 6.4 MB array) and ran at 130 us.

__global__ void zero_ints(int* __restrict__ p, int n) {
  int i = blockIdx.x * 256 + threadIdx.x;
  if (i < n) p[i] = 0;
}

__global__ void bucket_count(const int* __restrict__ dst_g2d, const int* __restrict__ dst_d2g,
                             int* __restrict__ bcnt) {
  __shared__ int h[NBK];
  for (int j = threadIdx.x; j < NBK; j += 256) h[j] = 0;
  __syncthreads();
  int stride = gridDim.x * 256;
  for (int i = blockIdx.x * 256 + threadIdx.x; i < 2 * NE; i += stride) {
    int d = (i < NE) ? dst_g2d[i] : ND + dst_d2g[i - NE];
    atomicAdd(&h[d >> 8], 1);
  }
  __syncthreads();
  for (int j = threadIdx.x; j < NBK; j += 256)
    if (h[j]) atomicAdd(&bcnt[j], h[j]);
}

__global__ void bucket_scan(const int* __restrict__ bcnt, int* __restrict__ bbase,
                            int* __restrict__ bcur) {
  __shared__ int s[1024];
  int t = threadIdx.x;
  s[t] = (t < NBK) ? bcnt[t] : 0;
  __syncthreads();
  for (int off = 1; off < 1024; off <<= 1) {
    int v = (t >= off) ? s[t - off] : 0;
    __syncthreads();
    s[t] += v;
    __syncthreads();
  }
  if (t < NBK) {
    int e = (t > 0) ? s[t - 1] : 0;
    bbase[t] = e;
    bcur[t] = e;
  }
  if (t == 0) bbase[NBK] = 2 * NE;
}

__global__ void bucket_scatter(const int* __restrict__ src_g2d, const int* __restrict__ dst_g2d,
                               const int* __restrict__ src_d2g, const int* __restrict__ dst_d2g,
                               int* __restrict__ bcur, int2* __restrict__ pairs) {
  __shared__ int h[NBK];
  __shared__ int base[NBK];
  int e0 = blockIdx.x * EPB;
  int e1 = e0 + EPB;
  if (e1 > 2 * NE) e1 = 2 * NE;
  for (int j = threadIdx.x; j < NBK; j += 256) h[j] = 0;
  __syncthreads();
  for (int i = e0 + threadIdx.x; i < e1; i += 256) {
    int d = (i < NE) ? dst_g2d[i] : ND + dst_d2g[i - NE];
    atomicAdd(&h[d >> 8], 1);
  }
  __syncthreads();
  for (int j = threadIdx.x; j < NBK; j += 256) {
    int c = h[j];
    base[j] = c ? atomicAdd(&bcur[j], c) : 0;
    h[j] = 0;  // reuse as local cursor
  }
  __syncthreads();
  for (int i = e0 + threadIdx.x; i < e1; i += 256) {
    int d, s;
    if (i < NE) {
      d = dst_g2d[i];
      s = src_g2d[i];
    } else {
      d = ND + dst_d2g[i - NE];
      s = src_d2g[i - NE];
    }
    int bkt = d >> 8;
    int p = base[bkt] + atomicAdd(&h[bkt], 1);
    pairs[p] = make_int2(d, s);
  }
}

__global__ void bucket_to_csr(const int* __restrict__ bbase, const int2* __restrict__ pairs,
                              int* __restrict__ off, int* __restrict__ csr) {
  __shared__ int cnt[256];
  __shared__ int ss[256];
  int b = blockIdx.x, t = threadIdx.x;
  int n0 = b << 8;
  int s0 = bbase[b], s1 = bbase[b + 1];
  cnt[t] = 0;
  __syncthreads();
  for (int i = s0 + t; i < s1; i += 256) atomicAdd(&cnt[pairs[i].x - n0], 1);
  __syncthreads();
  int x = cnt[t];
  ss[t] = x;
  __syncthreads();
  for (int o = 1; o < 256; o <<= 1) {
    int y = (t >= o) ? ss[t - o] : 0;
    __syncthreads();
    ss[t] += y;
    __syncthreads();
  }
  int abs0 = s0 + ss[t] - x;
  int node = n0 + t;
  if (node < NTOT) off[node] = abs0;
  if (node == NTOT - 1) off[NTOT] = 2 * NE;
  __syncthreads();
  cnt[t] = abs0;  // absolute cursor
  __syncthreads();
  for (int i = s0 + t; i < s1; i += 256) {
    int2 e = pairs[i];
    int p = atomicAdd(&cnt[e.x - n0], 1);
    csr[p] = e.y;
  }
}

// ---------------- fp32 -> bf16 table convert (RNE), both tables in one launch ------------

__global__ void to_bf16_all(const float* __restrict__ xg, const float* __restrict__ xd,
                            ushort* __restrict__ yg, ushort* __restrict__ yd) {
  int i = blockIdx.x * 256 + threadIdx.x;
  if (i >= NTOT * 16) return;
  const float* x;
  ushort* y;
  int j;
  if (i < NG * 16) {
    x = xg; y = yg; j = i;
  } else {
    x = xd; y = yd; j = i - NG * 16;
  }
  const float4* px = (const float4*)x;
  float4 a = px[2 * j], b = px[2 * j + 1];
  float v[8] = {a.x, a.y, a.z, a.w, b.x, b.y, b.z, b.w};
  uint32 u[4];
#pragma unroll
  for (int k = 0; k < 4; k++)
    u[k] = (uint32)rne_bf16(v[2 * k]) | ((uint32)rne_bf16(v[2 * k + 1]) << 16);
  ((int4*)y)[j] = make_int4((int)u[0], (int)u[1], (int)u[2], (int)u[3]);
}

// ---------------- W pre-split: fp32 -> bf16 hi (trunc) + bf16 lo (residual) --------------

__global__ void split_w(const float* __restrict__ Wl, const float* __restrict__ Wr,
                        ushort* __restrict__ WlH, ushort* __restrict__ WlL,
                        ushort* __restrict__ WrH, ushort* __restrict__ WrL) {
  int i = blockIdx.x * 256 + threadIdx.x;
  if (i >= 4 * 128 * 128) return;
  {
    float a = Wl[i];
    uint32 u = __builtin_bit_cast(uint32, a);
    float hf = __builtin_bit_cast(float, u & 0xffff0000u);
    WlH[i] = (ushort)(u >> 16);
    WlL[i] = (ushort)(__builtin_bit_cast(uint32, a - hf) >> 16);
  }
  {
    float a = Wr[i];
    uint32 u = __builtin_bit_cast(uint32, a);
    float hf = __builtin_bit_cast(float, u & 0xffff0000u);
    WrH[i] = (ushort)(u >> 16);
    WrL[i] = (ushort)(__builtin_bit_cast(uint32, a - hf) >> 16);
  }
}

// ---------------- mean aggregation over bf16 rows, unified node space --------------------
// 16 lanes per node (4 nodes per wave), 8-deep edge unroll.

__device__ __forceinline__ void acc8(float* a, int4 u) {
  uint32 w;
  w = (uint32)u.x;
  a[0] += __builtin_bit_cast(float, w << 16);
  a[1] += __builtin_bit_cast(float, w & 0xffff0000u);
  w = (uint32)u.y;
  a[2] += __builtin_bit_cast(float, w << 16);
  a[3] += __builtin_bit_cast(float, w & 0xffff0000u);
  w = (uint32)u.z;
  a[4] += __builtin_bit_cast(float, w << 16);
  a[5] += __builtin_bit_cast(float, w & 0xffff0000u);
  w = (uint32)u.w;
  a[6] += __builtin_bit_cast(float, w << 16);
  a[7] += __builtin_bit_cast(float, w & 0xffff0000u);
}

__global__ void agg_comb(const ushort* __restrict__ xg_bf, const ushort* __restrict__ xd_bf,
                         const int* __restrict__ off, const int* __restrict__ csr,
                         ushort* __restrict__ agg_bf) {
  int node = (blockIdx.x * 256 + threadIdx.x) >> 4;
  if (node >= NTOT) return;
  int l16 = threadIdx.x & 15;
  const int4* xs = (const int4*)((node < ND) ? xg_bf : xd_bf);
  int e0 = off[node], e1 = off[node + 1];
  float a[8] = {0.f, 0.f, 0.f, 0.f, 0.f, 0.f, 0.f, 0.f};
  int e = e0;
  for (; e + 7 < e1; e += 8) {
    int s[8];
#pragma unroll
    for (int j = 0; j < 8; j++) s[j] = csr[e + j];
    int4 v[8];
#pragma unroll
    for (int j = 0; j < 8; j++) v[j] = xs[(size_t)s[j] * 16 + l16];
#pragma unroll
    for (int j = 0; j < 8; j++) acc8(a, v[j]);
  }
  for (; e + 3 < e1; e += 4) {
    int s0 = csr[e], s1 = csr[e + 1], s2 = csr[e + 2], s3 = csr[e + 3];
    int4 v0 = xs[(size_t)s0 * 16 + l16];
    int4 v1 = xs[(size_t)s1 * 16 + l16];
    int4 v2 = xs[(size_t)s2 * 16 + l16];
    int4 v3 = xs[(size_t)s3 * 16 + l16];
    acc8(a, v0);
    acc8(a, v1);
    acc8(a, v2);
    acc8(a, v3);
  }
  for (; e + 1 < e1; e += 2) {
    int s0 = csr[e], s1 = csr[e + 1];
    int4 v0 = xs[(size_t)s0 * 16 + l16];
    int4 v1 = xs[(size_t)s1 * 16 + l16];
    acc8(a, v0);
    acc8(a, v1);
  }
  if (e < e1) acc8(a, xs[(size_t)csr[e] * 16 + l16]);
  int deg = e1 - e0;
  float inv = (deg > 0) ? 1.f / (float)deg : 0.f;
  uint32 u[4];
#pragma unroll
  for (int j = 0; j < 4; j++)
    u[j] = (uint32)rne_bf16(a[2 * j] * inv) | ((uint32)rne_bf16(a[2 * j + 1] * inv) << 16);
  *(int4*)&agg_bf[(size_t)node * DIM + l16 * 8] =
      make_int4((int)u[0], (int)u[1], (int)u[2], (int)u[3]);
}

// ---------------- MFMA SAGE update: acc[2][8], spill-free with full prefetch -------------
// (unchanged from R8 winner: WRITE_SIZE==112500 exactly, 65 us/dispatch)

__device__ __forceinline__ void split8v(float4 f0, float4 f1, bf16x8& hi, bf16x8& lo) {
  float v[8] = {f0.x, f0.y, f0.z, f0.w, f1.x, f1.y, f1.z, f1.w};
  uint32 hw[4], lw[4];
#pragma unroll
  for (int j = 0; j < 4; j++) {
    uint32 u0 = __builtin_bit_cast(uint32, v[2 * j]);
    uint32 u1 = __builtin_bit_cast(uint32, v[2 * j + 1]);
    float hf0 = __builtin_bit_cast(float, u0 & 0xffff0000u);
    float hf1 = __builtin_bit_cast(float, u1 & 0xffff0000u);
    uint32 l0 = __builtin_bit_cast(uint32, v[2 * j] - hf0) >> 16;
    uint32 l1 = __builtin_bit_cast(uint32, v[2 * j + 1] - hf1) >> 16;
    hw[j] = (u0 >> 16) | ((u1 >> 16) << 16);
    lw[j] = l0 | (l1 << 16);
  }
  hi = __builtin_bit_cast(bf16x8, make_int4((int)hw[0], (int)hw[1], (int)hw[2], (int)hw[3]));
  lo = __builtin_bit_cast(bf16x8, make_int4((int)lw[0], (int)lw[1], (int)lw[2], (int)lw[3]));
}

__launch_bounds__(256, 2)
__global__ void sage_dual(const ushort* __restrict__ agg_bf, const float* __restrict__ xd,
                          const float* __restrict__ xg, const ushort* __restrict__ WlH,
                          const ushort* __restrict__ WlL, const ushort* __restrict__ WrH,
                          const ushort* __restrict__ WrL, const float* __restrict__ bias_all,
                          float* __restrict__ outd, float* __restrict__ outg,
                          ushort* __restrict__ xbf_d, ushort* __restrict__ xbf_g, int layer,
                          int relu, int write_bf) {
  __shared__ __align__(16) char smem[65536];  // [hi 32K][lo 32K] of current phase's W

  int b = blockIdx.x;
  const float* X;
  float* O;
  ushort* OBF;
  int n, set, r0g, cbase;
  if (b < NBT_D3) {
    X = xd; O = outd; OBF = xbf_d; n = ND; set = layer * 2; r0g = b * RPB; cbase = 0;
  } else {
    X = xg; O = outg; OBF = xbf_g; n = NG; set = layer * 2 + 1;
    r0g = (b - NBT_D3) * RPB; cbase = ND;
  }
  const ushort* Wplanes[4] = {WlH + set * 16384, WlL + set * 16384, WrH + set * 16384,
                              WrL + set * 16384};
  const float* bias = bias_all + set * 128;

  int tid = threadIdx.x;
  int wave = tid >> 6, lane = tid & 63;
  int m = lane & 15, q = lane >> 4;
  int rb = r0g + wave * 32;

  int rp[2];
#pragma unroll
  for (int mt = 0; mt < 2; mt++) {
    int r = rb + mt * 16 + m;
    rp[mt] = (r >= n) ? (n - 1) : r;
  }

  // async stage hi/lo W planes: wave w covers 1KB chunks [w*16, w*16+16)
  auto stageW_async = [&](const ushort* Ph, const ushort* Pl) {
#pragma unroll
    for (int i = 0; i < 16; i++) {
      int cc = wave * 16 + i;            // 1KB chunk 0..63
      int dstb = cc * 1024 + lane * 16;  // linear LDS byte
      int p = cc >> 5;                   // plane (chunks don't straddle)
      int pb = dstb & 32767;
      int srcb = pb ^ (((pb >> 8) & 7) << 4);  // inverse swizzle on source
      const char* src = (const char*)(p ? Pl : Ph) + srcb;
      gload_lds16(src, smem + cc * 1024);
    }
  };

  // ---- prologue: issue Wl DMA + ALL ph0 A fragments (overlapped) ----
  stageW_async(Wplanes[0], Wplanes[1]);
  int4 aV[4][2];
#pragma unroll
  for (int ks = 0; ks < 4; ks++)
#pragma unroll
    for (int mt = 0; mt < 2; mt++)
      aV[ks][mt] = *(const int4*)&agg_bf[(size_t)(cbase + rp[mt]) * DIM + ks * 32 + q * 8];
  __syncthreads();  // drains vmcnt: DMA + A prefetch complete

  f32x4 acc[2][8];
#pragma unroll
  for (int mt = 0; mt < 2; mt++)
#pragma unroll
    for (int nt = 0; nt < 8; nt++) acc[mt][nt] = (f32x4)0.f;

  // ---- ph0: pure LDS + MFMA ----
#pragma unroll
  for (int ks = 0; ks < 4; ks++) {
    int kb = ks * 64 + q * 16;
#pragma unroll
    for (int nt = 0; nt < 8; nt++) {
      int nn = nt * 16 + m;
      int wb = (nn * 256 + kb) ^ ((nn & 7) << 4);
      bf16x8 bh = *(const bf16x8*)(smem + wb);
      bf16x8 bl = *(const bf16x8*)(smem + 32768 + wb);
#pragma unroll
      for (int mt = 0; mt < 2; mt++) {
        bf16x8 a = __builtin_bit_cast(bf16x8, aV[ks][mt]);
        acc[mt][nt] = __builtin_amdgcn_mfma_f32_16x16x32_bf16(a, bh, acc[mt][nt], 0, 0, 0);
        acc[mt][nt] = __builtin_amdgcn_mfma_f32_16x16x32_bf16(a, bl, acc[mt][nt], 0, 0, 0);
      }
    }
  }

  // ---- transition: issue ks0 X loads, then barrier, then Wr DMA ----
  float4 xV[2][2];
#pragma unroll
  for (int mt = 0; mt < 2; mt++) {
#pragma unroll
    for (int h = 0; h < 2; h++)
      xV[mt][h] = *(const float4*)&X[(size_t)rp[mt] * DIM + q * 8 + h * 4];
  }
  __syncthreads();  // ph0 LDS reads done (xV completes here too)
  stageW_async(Wplanes[2], Wplanes[3]);
  __syncthreads();  // Wr DMA complete

  // ---- ph1: root X, distance-1 prefetch of next ks ----
#pragma unroll
  for (int ks = 0; ks < 4; ks++) {
    int kb = ks * 64 + q * 16;
    bf16x8 ah[2], al[2];
#pragma unroll
    for (int mt = 0; mt < 2; mt++) split8v(xV[mt][0], xV[mt][1], ah[mt], al[mt]);
    if (ks < 3) {
#pragma unroll
      for (int mt = 0; mt < 2; mt++) {
#pragma unroll
        for (int h = 0; h < 2; h++)
          xV[mt][h] = *(const float4*)&X[(size_t)rp[mt] * DIM + (ks + 1) * 32 + q * 8 + h * 4];
      }
    }
#pragma unroll
    for (int nt = 0; nt < 8; nt++) {
      int nn = nt * 16 + m;
      int wb = (nn * 256 + kb) ^ ((nn & 7) << 4);
      bf16x8 bh = *(const bf16x8*)(smem + wb);
      bf16x8 bl = *(const bf16x8*)(smem + 32768 + wb);
#pragma unroll
      for (int mt = 0; mt < 2; mt++) {
        acc[mt][nt] = __builtin_amdgcn_mfma_f32_16x16x32_bf16(ah[mt], bh, acc[mt][nt], 0, 0, 0);
        acc[mt][nt] = __builtin_amdgcn_mfma_f32_16x16x32_bf16(ah[mt], bl, acc[mt][nt], 0, 0, 0);
        acc[mt][nt] = __builtin_amdgcn_mfma_f32_16x16x32_bf16(al[mt], bh, acc[mt][nt], 0, 0, 0);
      }
    }
  }
  __syncthreads();  // all waves done reading W LDS; epilogue aliases it

  // ---- epilogue: bias, relu, L2-normalize, skipsum, store (+ optional bf16 copy) ----
  float bb[8];
#pragma unroll
  for (int nt = 0; nt < 8; nt++) bb[nt] = bias[nt * 16 + m];

  const int S = 132;
  float* wbuf = (float*)smem + wave * (16 * S);  // wave-private: no barriers needed

  int half = lane >> 5;
  int c4 = (lane & 31) * 4;

#pragma unroll
  for (int mt = 0; mt < 2; mt++) {
#pragma unroll
    for (int reg = 0; reg < 4; reg++) {
      float h[8];
      float ss = 0.f;
#pragma unroll
      for (int nt = 0; nt < 8; nt++) {
        float v = acc[mt][nt][reg] + bb[nt];
        if (relu) v = fmaxf(v, 0.f);
        h[nt] = v;
        ss += v * v;
      }
      ss += __shfl_xor(ss, 1);
      ss += __shfl_xor(ss, 2);
      ss += __shfl_xor(ss, 4);
      ss += __shfl_xor(ss, 8);
      float inv = 1.f / fmaxf(sqrtf(ss), EPSN);
      int rrel = q * 4 + reg;
#pragma unroll
      for (int nt = 0; nt < 8; nt++) wbuf[rrel * S + nt * 16 + m] = h[nt] * inv;
    }
#pragma unroll
    for (int i = 0; i < 8; i++) {
      int rrel = i * 2 + half;
      int R = rb + mt * 16 + rrel;
      if (R < n) {
        f32x4 hv = *(const f32x4*)&wbuf[rrel * S + c4];
        float4 xr = *(const float4*)&X[(size_t)R * DIM + c4];
        float4 o;
        o.x = hv[0] + xr.x;
        o.y = hv[1] + xr.y;
        o.z = hv[2] + xr.z;
        o.w = hv[3] + xr.w;
        *(float4*)&O[(size_t)R * DIM + c4] = o;
        if (write_bf) {
          int2 pk = make_int2((int)((uint32)rne_bf16(o.x) | ((uint32)rne_bf16(o.y) << 16)),
                              (int)((uint32)rne_bf16(o.z) | ((uint32)rne_bf16(o.w) << 16)));
          *(int2*)&OBF[(size_t)R * DIM + c4] = pk;
        }
      }
    }
  }
}

// ---------------- launch ----------------

extern "C" void kernel_launch(void* const* d_in, const int* in_sizes, int n_in,
                              void* d_out, int out_size, void* d_ws, size_t ws_size,
                              hipStream_t stream) {
  const float* xg0 = (const float*)d_in[0];
  const float* xd0 = (const float*)d_in[1];
  const float* Wl = (const float*)d_in[2];
  const float* Wr = (const float*)d_in[3];
  const float* bs = (const float*)d_in[4];
  const int* src_g2d = (const int*)d_in[5];
  const int* dst_g2d = (const int*)d_in[6];
  const int* src_d2g = (const int*)d_in[7];
  const int* dst_d2g = (const int*)d_in[8];

  float* out_xg = (float*)d_out;
  float* out_xd = (float*)d_out + (size_t)NG * DIM;

  char* p = (char*)d_ws;
  auto alloc = [&](size_t bytes) -> char* {
    char* q = p;
    p += (bytes + 255) & ~(size_t)255;
    return q;
  };
  int* off = (int*)alloc((NTOT + 1) * 4);
  int* csr = (int*)alloc((size_t)2 * NE * 4);
  int* bcnt = (int*)alloc(NBK * 4);
  int* bbase = (int*)alloc((NBK + 1) * 4);
  int* bcur = (int*)alloc(NBK * 4);
  // pairs (12.8 MB, used only during CSR build) aliases agg_bf (38.4 MB, used after)
  char* big = alloc((size_t)NTOT * DIM * 2);
  int2* pairs = (int2*)big;
  ushort* agg_bf = (ushort*)big;
  ushort* xg_bf = (ushort*)alloc((size_t)NG * DIM * 2);
  ushort* xd_bf = (ushort*)alloc((size_t)ND * DIM * 2);
  ushort* WlH = (ushort*)alloc((size_t)4 * 128 * 128 * 2);
  ushort* WlL = (ushort*)alloc((size_t)4 * 128 * 128 * 2);
  ushort* WrH = (ushort*)alloc((size_t)4 * 128 * 128 * 2);
  ushort* WrL = (ushort*)alloc((size_t)4 * 128 * 128 * 2);

  const int TB = 256;

  split_w<<<256, TB, 0, stream>>>(Wl, Wr, WlH, WlL, WrH, WrL);
  to_bf16_all<<<(NTOT * 16 + TB - 1) / TB, TB, 0, stream>>>(xg0, xd0, xg_bf, xd_bf);

  // bucketed CSR build
  zero_ints<<<(NBK + TB - 1) / TB, TB, 0, stream>>>(bcnt, NBK);
  bucket_count<<<512, TB, 0, stream>>>(dst_g2d, dst_d2g, bcnt);
  bucket_scan<<<1, 1024, 0, stream>>>(bcnt, bbase, bcur);
  bucket_scatter<<<SCB, TB, 0, stream>>>(src_g2d, dst_g2d, src_d2g, dst_d2g, bcur, pairs);
  bucket_to_csr<<<NBK, TB, 0, stream>>>(bbase, pairs, off, csr);

  int aggBlocks = (NTOT * 16 + TB - 1) / TB;  // 9375 (16 lanes per node)
  int sageBlocks = NBT_D3 + NBT_G3;           // 1173

  // layer 0 (relu); sage also emits bf16 copy of out for layer-1 gather
  agg_comb<<<aggBlocks, TB, 0, stream>>>(xg_bf, xd_bf, off, csr, agg_bf);
  sage_dual<<<sageBlocks, TB, 0, stream>>>(agg_bf, xd0, xg0, WlH, WlL, WrH, WrL, bs, out_xd,
                                           out_xg, xd_bf, xg_bf, 0, 1, 1);

  // layer 1 (no relu), in-place on d_out
  agg_comb<<<aggBlocks, TB, 0, stream>>>(xg_bf, xd_bf, off, csr, agg_bf);
  sage_dual<<<sageBlocks, TB, 0, stream>>>(agg_bf, out_xd, out_xg, WlH, WlL, WrH, WrL, bs,
                                           out_xd, out_xg, xd_bf, xg_bf, 1, 0, 0);
}

// Round 11
// 434.420 us; speedup vs baseline: 1.3072x; 1.0169x over previous
//
#include <hip/hip_runtime.h>
#include <math.h>

#define NG 100000
#define ND 50000
#define NTOT 150000
#define DIM 128
#define NE 800000
#define EPSN 1e-12f

#define RPB 128     // rows per sage block
#define NBT_D3 391  // ceil(ND/128)
#define NBT_G3 782  // ceil(NG/128)

#define NBK 586   // ceil(NTOT/256) buckets of 256 dst nodes
#define SCB 512   // scatter blocks (2 blocks/CU)
#define EPB 3125  // edges per scatter block = 2*NE/SCB

typedef __bf16 bf16x8 __attribute__((ext_vector_type(8)));
typedef float f32x4 __attribute__((ext_vector_type(4)));
typedef unsigned int uint32;

__device__ __forceinline__ ushort rne_bf16(float f) {
  uint32 u = __builtin_bit_cast(uint32, f);
  u += 0x7fffu + ((u >> 16) & 1u);
  return (ushort)(u >> 16);
}

// async global->LDS, 16B per lane; LDS dest is wave-uniform base + lane*16
__device__ __forceinline__ void gload_lds16(const void* g, void* l) {
  __builtin_amdgcn_global_load_lds((const __attribute__((address_space(1))) void*)g,
                                   (__attribute__((address_space(3))) void*)l, 16, 0, 0);
}

// ---------------- bucketed CSR build ----------------
// unified dst space: disease dsts [0,ND), gene dsts [ND,NTOT). bucket = dst>>8.
// Two-phase (pairs intermediate) is deliberate: all writes are bucket-contiguous
// cache lines. R9's direct scatter_edges (random 4B csr writes) cost 17x write
// amplification (109 MB for a 6.4 MB array) and ran at 130 us.

__global__ void zero_ints(int* __restrict__ p, int n) {
  int i = blockIdx.x * 256 + threadIdx.x;
  if (i < n) p[i] = 0;
}

__global__ void bucket_count(const int* __restrict__ dst_g2d, const int* __restrict__ dst_d2g,
                             int* __restrict__ bcnt) {
  __shared__ int h[NBK];
  for (int j = threadIdx.x; j < NBK; j += 256) h[j] = 0;
  __syncthreads();
  int stride = gridDim.x * 256;
  for (int i = blockIdx.x * 256 + threadIdx.x; i < 2 * NE; i += stride) {
    int d = (i < NE) ? dst_g2d[i] : ND + dst_d2g[i - NE];
    atomicAdd(&h[d >> 8], 1);
  }
  __syncthreads();
  for (int j = threadIdx.x; j < NBK; j += 256)
    if (h[j]) atomicAdd(&bcnt[j], h[j]);
}

__global__ void bucket_scan(const int* __restrict__ bcnt, int* __restrict__ bbase,
                            int* __restrict__ bcur) {
  __shared__ int s[1024];
  int t = threadIdx.x;
  s[t] = (t < NBK) ? bcnt[t] : 0;
  __syncthreads();
  for (int off = 1; off < 1024; off <<= 1) {
    int v = (t >= off) ? s[t - off] : 0;
    __syncthreads();
    s[t] += v;
    __syncthreads();
  }
  if (t < NBK) {
    int e = (t > 0) ? s[t - 1] : 0;
    bbase[t] = e;
    bcur[t] = e;
  }
  if (t == 0) bbase[NBK] = 2 * NE;
}

__global__ void bucket_scatter(const int* __restrict__ src_g2d, const int* __restrict__ dst_g2d,
                               const int* __restrict__ src_d2g, const int* __restrict__ dst_d2g,
                               int* __restrict__ bcur, int2* __restrict__ pairs) {
  __shared__ int h[NBK];
  __shared__ int base[NBK];
  int e0 = blockIdx.x * EPB;
  int e1 = e0 + EPB;
  if (e1 > 2 * NE) e1 = 2 * NE;
  for (int j = threadIdx.x; j < NBK; j += 256) h[j] = 0;
  __syncthreads();
  for (int i = e0 + threadIdx.x; i < e1; i += 256) {
    int d = (i < NE) ? dst_g2d[i] : ND + dst_d2g[i - NE];
    atomicAdd(&h[d >> 8], 1);
  }
  __syncthreads();
  for (int j = threadIdx.x; j < NBK; j += 256) {
    int c = h[j];
    base[j] = c ? atomicAdd(&bcur[j], c) : 0;
    h[j] = 0;  // reuse as local cursor
  }
  __syncthreads();
  for (int i = e0 + threadIdx.x; i < e1; i += 256) {
    int d, s;
    if (i < NE) {
      d = dst_g2d[i];
      s = src_g2d[i];
    } else {
      d = ND + dst_d2g[i - NE];
      s = src_d2g[i - NE];
    }
    int bkt = d >> 8;
    int p = base[bkt] + atomicAdd(&h[bkt], 1);
    pairs[p] = make_int2(d, s);
  }
}

__global__ void bucket_to_csr(const int* __restrict__ bbase, const int2* __restrict__ pairs,
                              int* __restrict__ off, int* __restrict__ csr) {
  __shared__ int cnt[256];
  __shared__ int ss[256];
  int b = blockIdx.x, t = threadIdx.x;
  int n0 = b << 8;
  int s0 = bbase[b], s1 = bbase[b + 1];
  cnt[t] = 0;
  __syncthreads();
  for (int i = s0 + t; i < s1; i += 256) atomicAdd(&cnt[pairs[i].x - n0], 1);
  __syncthreads();
  int x = cnt[t];
  ss[t] = x;
  __syncthreads();
  for (int o = 1; o < 256; o <<= 1) {
    int y = (t >= o) ? ss[t - o] : 0;
    __syncthreads();
    ss[t] += y;
    __syncthreads();
  }
  int abs0 = s0 + ss[t] - x;
  int node = n0 + t;
  if (node < NTOT) off[node] = abs0;
  if (node == NTOT - 1) off[NTOT] = 2 * NE;
  __syncthreads();
  cnt[t] = abs0;  // absolute cursor
  __syncthreads();
  for (int i = s0 + t; i < s1; i += 256) {
    int2 e = pairs[i];
    int p = atomicAdd(&cnt[e.x - n0], 1);
    csr[p] = e.y;
  }
}

// ---------------- fp32 -> bf16 table convert (RNE), both tables in one launch ------------

__global__ void to_bf16_all(const float* __restrict__ xg, const float* __restrict__ xd,
                            ushort* __restrict__ yg, ushort* __restrict__ yd) {
  int i = blockIdx.x * 256 + threadIdx.x;
  if (i >= NTOT * 16) return;
  const float* x;
  ushort* y;
  int j;
  if (i < NG * 16) {
    x = xg; y = yg; j = i;
  } else {
    x = xd; y = yd; j = i - NG * 16;
  }
  const float4* px = (const float4*)x;
  float4 a = px[2 * j], b = px[2 * j + 1];
  float v[8] = {a.x, a.y, a.z, a.w, b.x, b.y, b.z, b.w};
  uint32 u[4];
#pragma unroll
  for (int k = 0; k < 4; k++)
    u[k] = (uint32)rne_bf16(v[2 * k]) | ((uint32)rne_bf16(v[2 * k + 1]) << 16);
  ((int4*)y)[j] = make_int4((int)u[0], (int)u[1], (int)u[2], (int)u[3]);
}

// ---------------- W pre-split: fp32 -> bf16 hi (trunc) + bf16 lo (residual) --------------

__global__ void split_w(const float* __restrict__ Wl, const float* __restrict__ Wr,
                        ushort* __restrict__ WlH, ushort* __restrict__ WlL,
                        ushort* __restrict__ WrH, ushort* __restrict__ WrL) {
  int i = blockIdx.x * 256 + threadIdx.x;
  if (i >= 4 * 128 * 128) return;
  {
    float a = Wl[i];
    uint32 u = __builtin_bit_cast(uint32, a);
    float hf = __builtin_bit_cast(float, u & 0xffff0000u);
    WlH[i] = (ushort)(u >> 16);
    WlL[i] = (ushort)(__builtin_bit_cast(uint32, a - hf) >> 16);
  }
  {
    float a = Wr[i];
    uint32 u = __builtin_bit_cast(uint32, a);
    float hf = __builtin_bit_cast(float, u & 0xffff0000u);
    WrH[i] = (ushort)(u >> 16);
    WrL[i] = (ushort)(__builtin_bit_cast(uint32, a - hf) >> 16);
  }
}

// ---------------- mean aggregation over bf16 rows, unified node space --------------------
// 16 lanes per node (4 nodes per wave), 8-deep edge unroll.

__device__ __forceinline__ void acc8(float* a, int4 u) {
  uint32 w;
  w = (uint32)u.x;
  a[0] += __builtin_bit_cast(float, w << 16);
  a[1] += __builtin_bit_cast(float, w & 0xffff0000u);
  w = (uint32)u.y;
  a[2] += __builtin_bit_cast(float, w << 16);
  a[3] += __builtin_bit_cast(float, w & 0xffff0000u);
  w = (uint32)u.z;
  a[4] += __builtin_bit_cast(float, w << 16);
  a[5] += __builtin_bit_cast(float, w & 0xffff0000u);
  w = (uint32)u.w;
  a[6] += __builtin_bit_cast(float, w << 16);
  a[7] += __builtin_bit_cast(float, w & 0xffff0000u);
}

__global__ void agg_comb(const ushort* __restrict__ xg_bf, const ushort* __restrict__ xd_bf,
                         const int* __restrict__ off, const int* __restrict__ csr,
                         ushort* __restrict__ agg_bf) {
  int node = (blockIdx.x * 256 + threadIdx.x) >> 4;
  if (node >= NTOT) return;
  int l16 = threadIdx.x & 15;
  const int4* xs = (const int4*)((node < ND) ? xg_bf : xd_bf);
  int e0 = off[node], e1 = off[node + 1];
  float a[8] = {0.f, 0.f, 0.f, 0.f, 0.f, 0.f, 0.f, 0.f};
  int e = e0;
  for (; e + 7 < e1; e += 8) {
    int s[8];
#pragma unroll
    for (int j = 0; j < 8; j++) s[j] = csr[e + j];
    int4 v[8];
#pragma unroll
    for (int j = 0; j < 8; j++) v[j] = xs[(size_t)s[j] * 16 + l16];
#pragma unroll
    for (int j = 0; j < 8; j++) acc8(a, v[j]);
  }
  for (; e + 3 < e1; e += 4) {
    int s0 = csr[e], s1 = csr[e + 1], s2 = csr[e + 2], s3 = csr[e + 3];
    int4 v0 = xs[(size_t)s0 * 16 + l16];
    int4 v1 = xs[(size_t)s1 * 16 + l16];
    int4 v2 = xs[(size_t)s2 * 16 + l16];
    int4 v3 = xs[(size_t)s3 * 16 + l16];
    acc8(a, v0);
    acc8(a, v1);
    acc8(a, v2);
    acc8(a, v3);
  }
  for (; e + 1 < e1; e += 2) {
    int s0 = csr[e], s1 = csr[e + 1];
    int4 v0 = xs[(size_t)s0 * 16 + l16];
    int4 v1 = xs[(size_t)s1 * 16 + l16];
    acc8(a, v0);
    acc8(a, v1);
  }
  if (e < e1) acc8(a, xs[(size_t)csr[e] * 16 + l16]);
  int deg = e1 - e0;
  float inv = (deg > 0) ? 1.f / (float)deg : 0.f;
  uint32 u[4];
#pragma unroll
  for (int j = 0; j < 4; j++)
    u[j] = (uint32)rne_bf16(a[2 * j] * inv) | ((uint32)rne_bf16(a[2 * j + 1] * inv) << 16);
  *(int4*)&agg_bf[(size_t)node * DIM + l16 * 8] =
      make_int4((int)u[0], (int)u[1], (int)u[2], (int)u[3]);
}

// ---------------- MFMA SAGE update: 512 threads, 8 waves x 16 rows, 4 waves/SIMD ---------
// Same 128-row tile, traffic, and DMA staging as the R8/R10 winner, but 8 waves of
// acc[1][8] instead of 4 waves of acc[2][8]: at __launch_bounds__(512,4) the unified
// budget is 128 regs/lane and the census is ~85 (acc 32 + aV 16 + xV 8 + temps), so
// still spill-free while DOUBLING waves/SIMD (2 -> 4) for latency hiding. LDS 68 KB
// (64 KB W planes + 8-wave epilogue buffers via alias), 2 blocks/CU.

__device__ __forceinline__ void split8v(float4 f0, float4 f1, bf16x8& hi, bf16x8& lo) {
  float v[8] = {f0.x, f0.y, f0.z, f0.w, f1.x, f1.y, f1.z, f1.w};
  uint32 hw[4], lw[4];
#pragma unroll
  for (int j = 0; j < 4; j++) {
    uint32 u0 = __builtin_bit_cast(uint32, v[2 * j]);
    uint32 u1 = __builtin_bit_cast(uint32, v[2 * j + 1]);
    float hf0 = __builtin_bit_cast(float, u0 & 0xffff0000u);
    float hf1 = __builtin_bit_cast(float, u1 & 0xffff0000u);
    uint32 l0 = __builtin_bit_cast(uint32, v[2 * j] - hf0) >> 16;
    uint32 l1 = __builtin_bit_cast(uint32, v[2 * j + 1] - hf1) >> 16;
    hw[j] = (u0 >> 16) | ((u1 >> 16) << 16);
    lw[j] = l0 | (l1 << 16);
  }
  hi = __builtin_bit_cast(bf16x8, make_int4((int)hw[0], (int)hw[1], (int)hw[2], (int)hw[3]));
  lo = __builtin_bit_cast(bf16x8, make_int4((int)lw[0], (int)lw[1], (int)lw[2], (int)lw[3]));
}

__launch_bounds__(512, 4)
__global__ void sage_dual(const ushort* __restrict__ agg_bf, const float* __restrict__ xd,
                          const float* __restrict__ xg, const ushort* __restrict__ WlH,
                          const ushort* __restrict__ WlL, const ushort* __restrict__ WrH,
                          const ushort* __restrict__ WrL, const float* __restrict__ bias_all,
                          float* __restrict__ outd, float* __restrict__ outg,
                          ushort* __restrict__ xbf_d, ushort* __restrict__ xbf_g, int layer,
                          int relu, int write_bf) {
  __shared__ __align__(16) char smem[69632];  // [Wl/Wr hi 32K][lo 32K] + epilogue headroom

  int b = blockIdx.x;
  const float* X;
  float* O;
  ushort* OBF;
  int n, set, r0g, cbase;
  if (b < NBT_D3) {
    X = xd; O = outd; OBF = xbf_d; n = ND; set = layer * 2; r0g = b * RPB; cbase = 0;
  } else {
    X = xg; O = outg; OBF = xbf_g; n = NG; set = layer * 2 + 1;
    r0g = (b - NBT_D3) * RPB; cbase = ND;
  }
  const ushort* Wplanes[4] = {WlH + set * 16384, WlL + set * 16384, WrH + set * 16384,
                              WrL + set * 16384};
  const float* bias = bias_all + set * 128;

  int tid = threadIdx.x;
  int wave = tid >> 6, lane = tid & 63;  // wave 0..7
  int m = lane & 15, q = lane >> 4;
  int rb = r0g + wave * 16;

  int r = rb + m;
  int rp = (r >= n) ? (n - 1) : r;

  // async stage hi/lo W planes: wave w covers 1KB chunks [w*8, w*8+8)
  auto stageW_async = [&](const ushort* Ph, const ushort* Pl) {
#pragma unroll
    for (int i = 0; i < 8; i++) {
      int cc = wave * 8 + i;             // 1KB chunk 0..63
      int dstb = cc * 1024 + lane * 16;  // linear LDS byte
      int p = cc >> 5;                   // plane (chunks don't straddle)
      int pb = dstb & 32767;
      int srcb = pb ^ (((pb >> 8) & 7) << 4);  // inverse swizzle on source
      const char* src = (const char*)(p ? Pl : Ph) + srcb;
      gload_lds16(src, smem + cc * 1024);
    }
  };

  // ---- prologue: issue Wl DMA + ALL ph0 A fragments (overlapped) ----
  stageW_async(Wplanes[0], Wplanes[1]);
  int4 aV[4];
#pragma unroll
  for (int ks = 0; ks < 4; ks++)
    aV[ks] = *(const int4*)&agg_bf[(size_t)(cbase + rp) * DIM + ks * 32 + q * 8];
  __syncthreads();  // drains vmcnt: DMA + A prefetch complete

  f32x4 acc[8];
#pragma unroll
  for (int nt = 0; nt < 8; nt++) acc[nt] = (f32x4)0.f;

  // ---- ph0: pure LDS + MFMA ----
#pragma unroll
  for (int ks = 0; ks < 4; ks++) {
    int kb = ks * 64 + q * 16;
    bf16x8 a = __builtin_bit_cast(bf16x8, aV[ks]);
#pragma unroll
    for (int nt = 0; nt < 8; nt++) {
      int nn = nt * 16 + m;
      int wb = (nn * 256 + kb) ^ ((nn & 7) << 4);
      bf16x8 bh = *(const bf16x8*)(smem + wb);
      bf16x8 bl = *(const bf16x8*)(smem + 32768 + wb);
      acc[nt] = __builtin_amdgcn_mfma_f32_16x16x32_bf16(a, bh, acc[nt], 0, 0, 0);
      acc[nt] = __builtin_amdgcn_mfma_f32_16x16x32_bf16(a, bl, acc[nt], 0, 0, 0);
    }
  }

  // ---- transition: issue ks0 X loads, then barrier, then Wr DMA ----
  float4 xV[2];
#pragma unroll
  for (int h = 0; h < 2; h++)
    xV[h] = *(const float4*)&X[(size_t)rp * DIM + q * 8 + h * 4];
  __syncthreads();  // ph0 LDS reads done (xV completes here too)
  stageW_async(Wplanes[2], Wplanes[3]);
  __syncthreads();  // Wr DMA complete

  // ---- ph1: root X, distance-1 prefetch of next ks ----
#pragma unroll
  for (int ks = 0; ks < 4; ks++) {
    int kb = ks * 64 + q * 16;
    bf16x8 ah, al;
    split8v(xV[0], xV[1], ah, al);
    if (ks < 3) {
#pragma unroll
      for (int h = 0; h < 2; h++)
        xV[h] = *(const float4*)&X[(size_t)rp * DIM + (ks + 1) * 32 + q * 8 + h * 4];
    }
#pragma unroll
    for (int nt = 0; nt < 8; nt++) {
      int nn = nt * 16 + m;
      int wb = (nn * 256 + kb) ^ ((nn & 7) << 4);
      bf16x8 bh = *(const bf16x8*)(smem + wb);
      bf16x8 bl = *(const bf16x8*)(smem + 32768 + wb);
      acc[nt] = __builtin_amdgcn_mfma_f32_16x16x32_bf16(ah, bh, acc[nt], 0, 0, 0);
      acc[nt] = __builtin_amdgcn_mfma_f32_16x16x32_bf16(ah, bl, acc[nt], 0, 0, 0);
      acc[nt] = __builtin_amdgcn_mfma_f32_16x16x32_bf16(al, bh, acc[nt], 0, 0, 0);
    }
  }
  __syncthreads();  // all waves done reading W LDS; epilogue aliases it

  // ---- epilogue: bias, relu, L2-normalize, skipsum, store (+ optional bf16 copy) ----
  float bb[8];
#pragma unroll
  for (int nt = 0; nt < 8; nt++) bb[nt] = bias[nt * 16 + m];

  const int S = 132;
  float* wbuf = (float*)smem + wave * (16 * S);  // wave-private: no barriers needed

  int half = lane >> 5;
  int c4 = (lane & 31) * 4;

#pragma unroll
  for (int reg = 0; reg < 4; reg++) {
    float h[8];
    float ss = 0.f;
#pragma unroll
    for (int nt = 0; nt < 8; nt++) {
      float v = acc[nt][reg] + bb[nt];
      if (relu) v = fmaxf(v, 0.f);
      h[nt] = v;
      ss += v * v;
    }
    ss += __shfl_xor(ss, 1);
    ss += __shfl_xor(ss, 2);
    ss += __shfl_xor(ss, 4);
    ss += __shfl_xor(ss, 8);
    float inv = 1.f / fmaxf(sqrtf(ss), EPSN);
    int rrel = q * 4 + reg;
#pragma unroll
    for (int nt = 0; nt < 8; nt++) wbuf[rrel * S + nt * 16 + m] = h[nt] * inv;
  }
#pragma unroll
  for (int i = 0; i < 8; i++) {
    int rrel = i * 2 + half;
    int R = rb + rrel;
    if (R < n) {
      f32x4 hv = *(const f32x4*)&wbuf[rrel * S + c4];
      float4 xr = *(const float4*)&X[(size_t)R * DIM + c4];
      float4 o;
      o.x = hv[0] + xr.x;
      o.y = hv[1] + xr.y;
      o.z = hv[2] + xr.z;
      o.w = hv[3] + xr.w;
      *(float4*)&O[(size_t)R * DIM + c4] = o;
      if (write_bf) {
        int2 pk = make_int2((int)((uint32)rne_bf16(o.x) | ((uint32)rne_bf16(o.y) << 16)),
                            (int)((uint32)rne_bf16(o.z) | ((uint32)rne_bf16(o.w) << 16)));
        *(int2*)&OBF[(size_t)R * DIM + c4] = pk;
      }
    }
  }
}

// ---------------- launch ----------------

extern "C" void kernel_launch(void* const* d_in, const int* in_sizes, int n_in,
                              void* d_out, int out_size, void* d_ws, size_t ws_size,
                              hipStream_t stream) {
  const float* xg0 = (const float*)d_in[0];
  const float* xd0 = (const float*)d_in[1];
  const float* Wl = (const float*)d_in[2];
  const float* Wr = (const float*)d_in[3];
  const float* bs = (const float*)d_in[4];
  const int* src_g2d = (const int*)d_in[5];
  const int* dst_g2d = (const int*)d_in[6];
  const int* src_d2g = (const int*)d_in[7];
  const int* dst_d2g = (const int*)d_in[8];

  float* out_xg = (float*)d_out;
  float* out_xd = (float*)d_out + (size_t)NG * DIM;

  char* p = (char*)d_ws;
  auto alloc = [&](size_t bytes) -> char* {
    char* q = p;
    p += (bytes + 255) & ~(size_t)255;
    return q;
  };
  int* off = (int*)alloc((NTOT + 1) * 4);
  int* csr = (int*)alloc((size_t)2 * NE * 4);
  int* bcnt = (int*)alloc(NBK * 4);
  int* bbase = (int*)alloc((NBK + 1) * 4);
  int* bcur = (int*)alloc(NBK * 4);
  // pairs (12.8 MB, used only during CSR build) aliases agg_bf (38.4 MB, used after)
  char* big = alloc((size_t)NTOT * DIM * 2);
  int2* pairs = (int2*)big;
  ushort* agg_bf = (ushort*)big;
  ushort* xg_bf = (ushort*)alloc((size_t)NG * DIM * 2);
  ushort* xd_bf = (ushort*)alloc((size_t)ND * DIM * 2);
  ushort* WlH = (ushort*)alloc((size_t)4 * 128 * 128 * 2);
  ushort* WlL = (ushort*)alloc((size_t)4 * 128 * 128 * 2);
  ushort* WrH = (ushort*)alloc((size_t)4 * 128 * 128 * 2);
  ushort* WrL = (ushort*)alloc((size_t)4 * 128 * 128 * 2);

  const int TB = 256;

  split_w<<<256, TB, 0, stream>>>(Wl, Wr, WlH, WlL, WrH, WrL);
  to_bf16_all<<<(NTOT * 16 + TB - 1) / TB, TB, 0, stream>>>(xg0, xd0, xg_bf, xd_bf);

  // bucketed CSR build
  zero_ints<<<(NBK + TB - 1) / TB, TB, 0, stream>>>(bcnt, NBK);
  bucket_count<<<512, TB, 0, stream>>>(dst_g2d, dst_d2g, bcnt);
  bucket_scan<<<1, 1024, 0, stream>>>(bcnt, bbase, bcur);
  bucket_scatter<<<SCB, TB, 0, stream>>>(src_g2d, dst_g2d, src_d2g, dst_d2g, bcur, pairs);
  bucket_to_csr<<<NBK, TB, 0, stream>>>(bbase, pairs, off, csr);

  int aggBlocks = (NTOT * 16 + TB - 1) / TB;  // 9375 (16 lanes per node)
  int sageBlocks = NBT_D3 + NBT_G3;           // 1173

  // layer 0 (relu); sage also emits bf16 copy of out for layer-1 gather
  agg_comb<<<aggBlocks, TB, 0, stream>>>(xg_bf, xd_bf, off, csr, agg_bf);
  sage_dual<<<sageBlocks, 512, 0, stream>>>(agg_bf, xd0, xg0, WlH, WlL, WrH, WrL, bs, out_xd,
                                            out_xg, xd_bf, xg_bf, 0, 1, 1);

  // layer 1 (no relu), in-place on d_out
  agg_comb<<<aggBlocks, TB, 0, stream>>>(xg_bf, xd_bf, off, csr, agg_bf);
  sage_dual<<<sageBlocks, 512, 0, stream>>>(agg_bf, out_xd, out_xg, WlH, WlL, WrH, WrL, bs,
                                            out_xd, out_xg, xd_bf, xg_bf, 1, 0, 0);
}